// Round 4
// baseline (82.263 us; speedup 1.0000x reference)
//
#include <hip/hip_runtime.h>
#include <hip/hip_bf16.h>

// Euler characteristic curve (ECC) of V-construction cubical complex.
// x: [64,3,224,224] fp32 in [0,1). Out: [64,96] fp32 = per-(b,c) ECC over
// tseq = linspace(0,1,32); out[img*32+t], img = b*3+c.
//
// Cell->bin: bin(f) = ceil(31*f); monotonic so bin(max) = max(bin).
// Per pixel, 4 cells collapse to two signed run-boundary pairs:
//   pair1 (vertex/h-edge): fires iff B_{k+1} > B_k:   +1@B_k, -1@B_{k+1}
//   pair2 (v-edge/square), M_k = max(B_k,C_k): fires iff M_{k+1} > M_k:
//                                                      -1@M_k, +1@M_{k+1}
// Sentinels: missing-right -> 33, missing-below -> 32; spurious updates land
// in garbage bins 32/33 (discarded at reduce). Verified absmax=0 in R3.
//
// R4: full unroll of the 7-row loop with ALL row loads hoisted upfront
// (8 float4 + 8 scalar in flight -> vmcnt-pipelined), launch_bounds(256,6)
// so all 6 grid blocks/CU are resident (24 waves/CU). Attacks R3's exposed
// per-iteration load latency (serial load->bins->atomics chain).

#define H 224
#define W 224
#define STEPS 32
#define NBINS 34            // 32 real + garbage bins 32 (no-below), 33 (no-right)
#define NCOL 64
#define BANDS 8
#define BAND_ROWS 28        // per block
#define SUB_ROWS 7          // per wave (4 waves per block)
#define NTHR 256

__device__ __forceinline__ int bin_of(float f) {
    int i = (int)ceilf(f * 31.0f);   // f in [0,1) -> [0,31]
    return i > 31 ? 31 : i;          // defensive clamp
}

__global__ __launch_bounds__(NTHR, 6) void ecc_hist_kernel(
        const float* __restrict__ x, int* __restrict__ ghist)
{
    // Shared across the block's 4 waves. Update addr = (bin*64 + c)*4:
    // bank = c%32 -> 2-way wave aliasing (free, m136).
    __shared__ int lh[NBINS * NCOL];     // 8704 B
    __shared__ int partial[NTHR];        // 1 KB

    const int tid = threadIdx.x;
    #pragma unroll
    for (int i = tid; i < NBINS * NCOL; i += NTHR) lh[i] = 0;
    __syncthreads();

    const int band = blockIdx.x & (BANDS - 1);
    const int img  = blockIdx.x / BANDS;          // 0..191
    const float* __restrict__ p = x + (size_t)img * (H * W);

    const int c = tid & 63;      // column group: cols 4c..4c+3 (active c<56)
    const int s = tid >> 6;      // sub-band id == wave id (rows uniform per wave)

    if (c < 56) {
        const int  j0    = c << 2;
        const bool lastc = (c == 55);
        const int  jn    = lastc ? (j0 + 3) : (j0 + 4);  // in-bounds; lastc value overridden
        const int  r0    = band * BAND_ROWS + s * SUB_ROWS;
        int* __restrict__ lhc = lh + c;

        // Hoist all 8 row loads (row r0..r0+7); row index clamped to H-1 for
        // the one wave whose 8th row is OOB (its bins get sentinel'd anyway).
        float4 R[SUB_ROWS + 1];
        float  E[SUB_ROWS + 1];
        #pragma unroll
        for (int k = 0; k <= SUB_ROWS; ++k) {
            int rr = r0 + k;
            rr = rr > (H - 1) ? (H - 1) : rr;
            const float* __restrict__ row = p + rr * W;
            R[k] = *(const float4*)(row + j0);
            E[k] = row[jn];
        }

        int B0 = bin_of(R[0].x), B1 = bin_of(R[0].y),
            B2 = bin_of(R[0].z), B3 = bin_of(R[0].w);
        int Bn = lastc ? 33 : bin_of(E[0]);

        #pragma unroll
        for (int k = 0; k < SUB_ROWS; ++k) {
            int C0, C1, C2, C3, Cn;
            if (r0 + k < H - 1) {                 // wave-uniform
                C0 = bin_of(R[k + 1].x); C1 = bin_of(R[k + 1].y);
                C2 = bin_of(R[k + 1].z); C3 = bin_of(R[k + 1].w);
                Cn = lastc ? 33 : bin_of(E[k + 1]);
            } else {
                C0 = C1 = C2 = C3 = 32; Cn = 32;  // kill pair2 on bottom row
            }

            // pair1: vertex/h-edge run boundaries along the B row
            if (B1 > B0) { atomicAdd(&lhc[B0 << 6],  1); atomicAdd(&lhc[B1 << 6], -1); }
            if (B2 > B1) { atomicAdd(&lhc[B1 << 6],  1); atomicAdd(&lhc[B2 << 6], -1); }
            if (B3 > B2) { atomicAdd(&lhc[B2 << 6],  1); atomicAdd(&lhc[B3 << 6], -1); }
            if (Bn > B3) { atomicAdd(&lhc[B3 << 6],  1); atomicAdd(&lhc[Bn << 6], -1); }

            // pair2: v-edge/square run boundaries along M_k = max(B_k, C_k)
            {
                int M0 = max(B0, C0), M1 = max(B1, C1), M2 = max(B2, C2),
                    M3 = max(B3, C3), Mn = max(Bn, Cn);
                if (M1 > M0) { atomicAdd(&lhc[M0 << 6], -1); atomicAdd(&lhc[M1 << 6], 1); }
                if (M2 > M1) { atomicAdd(&lhc[M1 << 6], -1); atomicAdd(&lhc[M2 << 6], 1); }
                if (M3 > M2) { atomicAdd(&lhc[M2 << 6], -1); atomicAdd(&lhc[M3 << 6], 1); }
                if (Mn > M3) { atomicAdd(&lhc[M3 << 6], -1); atomicAdd(&lhc[Mn << 6], 1); }
            }

            B0 = C0; B1 = C1; B2 = C2; B3 = C3; Bn = Cn;
        }
    }
    __syncthreads();

    // Reduce 64 columns -> 32 bins (garbage bins 32/33 dropped).
    const int b = tid >> 3;              // 0..31
    const int g = tid & 7;               // 8 col-groups of 8
    const int4* row = (const int4*)(lh + (b << 6) + (g << 3));
    int4 v0 = row[0], v1 = row[1];
    partial[tid] = v0.x + v0.y + v0.z + v0.w + v1.x + v1.y + v1.z + v1.w;
    __syncthreads();

    if (tid < 32) {
        const int4* pr = (const int4*)(partial + (tid << 3));
        int4 a0 = pr[0], a1 = pr[1];
        int s8 = a0.x + a0.y + a0.z + a0.w + a1.x + a1.y + a1.z + a1.w;
        atomicAdd(&ghist[img * STEPS + tid], s8);
    }
}

__global__ void ecc_cumsum_kernel(const int* __restrict__ ghist,
                                  float* __restrict__ out, int nimg)
{
    int img = blockIdx.x * blockDim.x + threadIdx.x;
    if (img < nimg) {
        int s = 0;
        #pragma unroll
        for (int t = 0; t < STEPS; ++t) {
            s += ghist[img * STEPS + t];
            out[img * STEPS + t] = (float)s;
        }
    }
}

extern "C" void kernel_launch(void* const* d_in, const int* in_sizes, int n_in,
                              void* d_out, int out_size, void* d_ws, size_t ws_size,
                              hipStream_t stream) {
    const float* x = (const float*)d_in[0];
    float* out = (float*)d_out;
    int* ghist = (int*)d_ws;

    const int nimg = in_sizes[0] / (H * W);      // 192

    hipMemsetAsync(ghist, 0, (size_t)nimg * STEPS * sizeof(int), stream);

    dim3 grid1(nimg * BANDS);
    ecc_hist_kernel<<<grid1, NTHR, 0, stream>>>(x, ghist);

    int thr2 = 256;
    int blk2 = (nimg + thr2 - 1) / thr2;
    ecc_cumsum_kernel<<<blk2, thr2, 0, stream>>>(ghist, out, nimg);
}

// Round 5
// 79.150 us; speedup vs baseline: 1.0393x; 1.0393x over previous
//
#include <hip/hip_runtime.h>
#include <hip/hip_bf16.h>

// Euler characteristic curve (ECC) of V-construction cubical complex.
// x: [64,3,224,224] fp32 in [0,1). Out: [64,96] fp32 = per-(b,c) ECC over
// tseq = linspace(0,1,32); out[img*32+t], img = b*3+c.
//
// Cell->bin: bin(f) = ceil(31*f); monotonic so bin(max) = max(bin).
// Per pixel, 4 cells collapse to two signed run-boundary pairs:
//   pair1 (vertex/h-edge): fires iff B_{k+1} > B_k:   +1@B_k, -1@B_{k+1}
//   pair2 (v-edge/square), M_k = max(B_k,C_k): fires iff M_{k+1} > M_k:
//                                                      -1@M_k, +1@M_{k+1}
// Sentinels: missing-right -> 33, missing-below -> 32; spurious updates land
// in garbage bins 32/33 (discarded at reduce). Verified absmax=0 (R3/R4).
//
// R5: drop the ghist memset launch entirely — each hist block PLAIN-STORES its
// 32-bin partial to a distinct slot part[img][band][...] (overwrites the 0xAA
// poison, no zero-init, no global atomics); cumsum kernel sums the 8 bands and
// shfl-scans. Also reverts R4's register hoist (compiler already unrolls the
// trip-7 loop; hoist only added VGPR pressure) back to the lean R3 body.

#define H 224
#define W 224
#define STEPS 32
#define NBINS 34            // 32 real + garbage bins 32 (no-below), 33 (no-right)
#define NCOL 64
#define BANDS 8
#define BAND_ROWS 28        // per block
#define SUB_ROWS 7          // per wave (4 waves per block)
#define NTHR 256

__device__ __forceinline__ int bin_of(float f) {
    int i = (int)ceilf(f * 31.0f);   // f in [0,1) -> [0,31]
    return i > 31 ? 31 : i;          // defensive clamp
}

__global__ __launch_bounds__(NTHR, 6) void ecc_hist_kernel(
        const float* __restrict__ x, int* __restrict__ part)
{
    // Shared across the block's 4 waves. Update addr = (bin*64 + c)*4:
    // bank = c%32 -> 2-way wave aliasing (free, m136).
    __shared__ int lh[NBINS * NCOL];     // 8704 B
    __shared__ int partial[NTHR];        // 1 KB

    const int tid = threadIdx.x;
    #pragma unroll
    for (int i = tid; i < NBINS * NCOL; i += NTHR) lh[i] = 0;
    __syncthreads();

    const int band = blockIdx.x & (BANDS - 1);
    const int img  = blockIdx.x / BANDS;          // 0..191
    const float* __restrict__ p = x + (size_t)img * (H * W);

    const int c = tid & 63;      // column group: cols 4c..4c+3 (active c<56)
    const int s = tid >> 6;      // sub-band id == wave id (rows uniform per wave)

    if (c < 56) {
        const int  j0    = c << 2;
        const bool lastc = (c == 55);
        const int  jn    = lastc ? (j0 + 3) : (j0 + 4);  // in-bounds; lastc overridden
        const int  r0    = band * BAND_ROWS + s * SUB_ROWS;
        int* __restrict__ lhc = lh + c;

        float4 F = *(const float4*)(p + r0 * W + j0);
        float  fn = p[r0 * W + jn];
        int B0 = bin_of(F.x), B1 = bin_of(F.y), B2 = bin_of(F.z), B3 = bin_of(F.w);
        int Bn = lastc ? 33 : bin_of(fn);

        for (int r = r0; r < r0 + SUB_ROWS; ++r) {
            int C0, C1, C2, C3, Cn;
            if (r < H - 1) {                      // wave-uniform
                float4 G = *(const float4*)(p + (r + 1) * W + j0);
                float  gn = p[(r + 1) * W + jn];
                C0 = bin_of(G.x); C1 = bin_of(G.y); C2 = bin_of(G.z); C3 = bin_of(G.w);
                Cn = lastc ? 33 : bin_of(gn);
            } else {
                C0 = C1 = C2 = C3 = 32; Cn = 32;  // kill pair2 on bottom row
            }

            // pair1: vertex/h-edge run boundaries along the B row
            if (B1 > B0) { atomicAdd(&lhc[B0 << 6],  1); atomicAdd(&lhc[B1 << 6], -1); }
            if (B2 > B1) { atomicAdd(&lhc[B1 << 6],  1); atomicAdd(&lhc[B2 << 6], -1); }
            if (B3 > B2) { atomicAdd(&lhc[B2 << 6],  1); atomicAdd(&lhc[B3 << 6], -1); }
            if (Bn > B3) { atomicAdd(&lhc[B3 << 6],  1); atomicAdd(&lhc[Bn << 6], -1); }

            // pair2: v-edge/square run boundaries along M_k = max(B_k, C_k)
            {
                int M0 = max(B0, C0), M1 = max(B1, C1), M2 = max(B2, C2),
                    M3 = max(B3, C3), Mn = max(Bn, Cn);
                if (M1 > M0) { atomicAdd(&lhc[M0 << 6], -1); atomicAdd(&lhc[M1 << 6], 1); }
                if (M2 > M1) { atomicAdd(&lhc[M1 << 6], -1); atomicAdd(&lhc[M2 << 6], 1); }
                if (M3 > M2) { atomicAdd(&lhc[M2 << 6], -1); atomicAdd(&lhc[M3 << 6], 1); }
                if (Mn > M3) { atomicAdd(&lhc[M3 << 6], -1); atomicAdd(&lhc[Mn << 6], 1); }
            }

            B0 = C0; B1 = C1; B2 = C2; B3 = C3; Bn = Cn;
        }
    }
    __syncthreads();

    // Reduce 64 columns -> 32 bins (garbage bins 32/33 dropped).
    const int b = tid >> 3;              // 0..31
    const int g = tid & 7;               // 8 col-groups of 8
    const int4* row = (const int4*)(lh + (b << 6) + (g << 3));
    int4 v0 = row[0], v1 = row[1];
    partial[tid] = v0.x + v0.y + v0.z + v0.w + v1.x + v1.y + v1.z + v1.w;
    __syncthreads();

    if (tid < 32) {
        const int4* pr = (const int4*)(partial + (tid << 3));
        int4 a0 = pr[0], a1 = pr[1];
        int s8 = a0.x + a0.y + a0.z + a0.w + a1.x + a1.y + a1.z + a1.w;
        // Plain store to this block's OWN slot — overwrites poison, no init.
        part[(((img << 3) | band) << 5) + tid] = s8;
    }
}

// One block (64 threads, lanes 0..31 active) per image: sum 8 band-partials
// per bin, inclusive shfl-scan across bins, write floats.
__global__ __launch_bounds__(64) void ecc_cumsum_kernel(
        const int* __restrict__ part, float* __restrict__ out)
{
    const int img  = blockIdx.x;
    const int lane = threadIdx.x;
    if (lane < STEPS) {
        const int* pb = part + (img << 8) + lane;   // img*8*32 + lane
        int s = 0;
        #pragma unroll
        for (int band = 0; band < BANDS; ++band) s += pb[band << 5];
        // inclusive prefix over lanes 0..31
        #pragma unroll
        for (int off = 1; off < STEPS; off <<= 1) {
            int v = __shfl_up(s, off);
            if (lane >= off) s += v;
        }
        out[img * STEPS + lane] = (float)s;
    }
}

extern "C" void kernel_launch(void* const* d_in, const int* in_sizes, int n_in,
                              void* d_out, int out_size, void* d_ws, size_t ws_size,
                              hipStream_t stream) {
    const float* x = (const float*)d_in[0];
    float* out = (float*)d_out;
    int* part = (int*)d_ws;                      // [192][8][32] ints

    const int nimg = in_sizes[0] / (H * W);      // 192

    dim3 grid1(nimg * BANDS);
    ecc_hist_kernel<<<grid1, NTHR, 0, stream>>>(x, part);

    ecc_cumsum_kernel<<<dim3(nimg), 64, 0, stream>>>(part, out);
}